// Round 8
// baseline (42606.717 us; speedup 1.0000x reference)
//
#include <hip/hip_runtime.h>
#include <hip/hip_bf16.h>
#include <math.h>

#define GBK 256          // grid blocks (1 per CU, co-resident)
#define NT  512          // threads per block (8 waves)

constexpr int T_STEPS = 600;
constexpr int TXT     = 200;
constexpr int NMEL    = 80;
constexpr int H       = 1024;
constexpr int ATT     = 640;
constexpr int DIN     = H + ATT;   // 1664
constexpr int GATE_B  = 200;       // gate-output block

// ---- ws layout: bf16 region (ushort element offsets) ----
constexpr size_t O_WQ    = 0;                                  // 640*1024
constexpr size_t O_WIHA  = O_WQ   + (size_t)ATT*H;             // 4096*80
constexpr size_t O_WIH0  = O_WIHA + (size_t)4*H*NMEL;          // 4096*1664
constexpr size_t O_WHH1  = O_WIH0 + (size_t)4*H*DIN;           // 4096*1024
constexpr size_t O_WD1   = O_WHH1 + (size_t)4*H*H;             // 1024*1024
constexpr size_t O_WD2   = O_WD1  + (size_t)H*H;
constexpr size_t O_KEYS  = O_WD2  + (size_t)H*H;               // 200*640 row-major
constexpr size_t O_VALT  = O_KEYS + (size_t)TXT*ATT;           // 640*200 transposed
constexpr size_t O_END_U = O_VALT + (size_t)TXT*ATT;
constexpr size_t FBYTE   = ((O_END_U*2 + 255)/256)*256;
// ---- float region (float element offsets); single-buffered handoff vectors ----
constexpr int F_X   = 0;           // 128 (80 used)
constexpr int F_HA  = 128;         // H
constexpr int F_H0  = F_HA + H;    // H
constexpr int F_H1  = F_H0 + H;    // H
constexpr int F_Q   = F_H1 + H;    // ATT
constexpr int F_D1  = F_Q  + ATT;  // H
constexpr int F_D   = F_D1 + H;    // H
constexpr int F_END = F_D  + H;
constexpr size_t BBYTE  = FBYTE + (((size_t)F_END*4 + 255)/256)*256;
// barrier flags: 64 lines x 128B; block b -> line b>>2, dword b&3
constexpr int BAR_N = 64*32;

typedef unsigned short ushortT;
typedef ushortT us4 __attribute__((ext_vector_type(4)));
typedef ushortT us8 __attribute__((ext_vector_type(8)));

__device__ __forceinline__ float bf2f(ushortT u) {
  return __uint_as_float(((unsigned)u) << 16);
}
__device__ __forceinline__ ushortT f2bf(float x) {
  __hip_bfloat16 h = __float2bfloat16(x);
  ushortT u; __builtin_memcpy(&u, &h, 2); return u;
}
__device__ __forceinline__ us4 cvt4(float4 a) {
  return us4{ f2bf(a.x), f2bf(a.y), f2bf(a.z), f2bf(a.w) };
}
__device__ __forceinline__ float sigf(float x) { return 1.0f / (1.0f + expf(-x)); }
__device__ __forceinline__ float tanhfast(float x) {
  float e = __expf(2.0f * x);
  return (e - 1.0f) / (e + 1.0f);
}

__device__ __forceinline__ float red64(float v) {
  #pragma unroll
  for (int off = 32; off > 0; off >>= 1) v += __shfl_xor(v, off, 64);
  return v;
}

// coherent accessors (LLC, cache-bypassing)
__device__ __forceinline__ float cload(const float* p) {
  return __hip_atomic_load(p, __ATOMIC_RELAXED, __HIP_MEMORY_SCOPE_AGENT);
}
__device__ __forceinline__ void cstore(float* p, float v) {
  __hip_atomic_store(p, v, __ATOMIC_RELAXED, __HIP_MEMORY_SCOPE_AGENT);
}
__device__ __forceinline__ unsigned aload(const unsigned* p) {
  return __hip_atomic_load(p, __ATOMIC_RELAXED, __HIP_MEMORY_SCOPE_AGENT);
}
__device__ __forceinline__ void astore(unsigned* p, unsigned v) {
  __hip_atomic_store(p, v, __ATOMIC_RELAXED, __HIP_MEMORY_SCOPE_AGENT);
}
// 16B coherent loads (load + waitcnt in ONE asm so no consumer can be hoisted)
__device__ __forceinline__ float4 cload4(const float* p) {
  float4 v;
  asm volatile("global_load_dwordx4 %0, %1, off sc0 sc1\n\ts_waitcnt vmcnt(0)"
               : "=v"(v) : "v"(p) : "memory");
  return v;
}
__device__ __forceinline__ uint4 cloadu4(const unsigned* p) {
  uint4 v;
  asm volatile("global_load_dwordx4 %0, %1, off sc0 sc1\n\ts_waitcnt vmcnt(0)"
               : "=v"(v) : "v"(p) : "memory");
  return v;
}
__device__ __forceinline__ void cstage4(float* dst, const float* src, int nf4) {
  for (int i = threadIdx.x; i < nf4; i += NT)
    ((float4*)dst)[i] = cload4(src + i*4);
}

// ---- conflict-free dots: lane handles float4/us4 index c*64+lane ----
__device__ __forceinline__ float dotbf(const ushortT* __restrict__ Wrow,
                                       const float* __restrict__ v, int lane) {
  const us4* w4 = (const us4*)Wrow;
  const float4* v4 = (const float4*)v;
  float s = 0.f;
  #pragma unroll
  for (int c = 0; c < 4; ++c) {
    us4 w = w4[c*64 + lane];
    float4 x = v4[c*64 + lane];
    s += bf2f(w[0])*x.x + bf2f(w[1])*x.y + bf2f(w[2])*x.z + bf2f(w[3])*x.w;
  }
  return s;
}
__device__ __forceinline__ float dot640bf(const ushortT* __restrict__ Wrow,
                                          const float* __restrict__ v, int lane) {
  const us4* w4 = (const us4*)Wrow;
  const float4* v4 = (const float4*)v;
  float s = 0.f;
  #pragma unroll
  for (int c = 0; c < 2; ++c) {
    us4 w = w4[c*64 + lane];
    float4 x = v4[c*64 + lane];
    s += bf2f(w[0])*x.x + bf2f(w[1])*x.y + bf2f(w[2])*x.z + bf2f(w[3])*x.w;
  }
  if (lane < 32) {
    us4 w = w4[128 + lane];
    float4 x = v4[128 + lane];
    s += bf2f(w[0])*x.x + bf2f(w[1])*x.y + bf2f(w[2])*x.z + bf2f(w[3])*x.w;
  }
  return s;
}
__device__ __forceinline__ float dotf(const float* __restrict__ Wrow,
                                      const float* __restrict__ v, int lane) {
  const float4* w4 = (const float4*)Wrow;
  const float4* v4 = (const float4*)v;
  float s = 0.f;
  #pragma unroll
  for (int c = 0; c < 4; ++c) {
    float4 w = w4[c*64 + lane], x = v4[c*64 + lane];
    s += w.x*x.x + w.y*x.y + w.z*x.z + w.w*x.w;
  }
  return s;
}
__device__ __forceinline__ float dot640f(const float* __restrict__ Wrow,
                                         const float* __restrict__ v, int lane) {
  const float4* w4 = (const float4*)Wrow;
  const float4* v4 = (const float4*)v;
  float s = 0.f;
  #pragma unroll
  for (int c = 0; c < 2; ++c) {
    float4 w = w4[c*64 + lane], x = v4[c*64 + lane];
    s += w.x*x.x + w.y*x.y + w.z*x.z + w.w*x.w;
  }
  if (lane < 32) {
    float4 w = w4[128 + lane], x = v4[128 + lane];
    s += w.x*x.x + w.y*x.y + w.z*x.z + w.w*x.w;
  }
  return s;
}

// single-hop all-to-all grid barrier; packed flags -> one dwordx4 poll per lane
__device__ __forceinline__ void abar(unsigned* bar, int bid, unsigned n) {
  asm volatile("s_waitcnt vmcnt(0)" ::: "memory");
  __syncthreads();
  const int tid = threadIdx.x;
  if (tid == 0) astore(bar + (bid >> 2)*32 + (bid & 3), n);
  if (tid < 64) {
    const unsigned* p = bar + tid*32;
    while (true) {
      uint4 v = cloadu4(p);
      unsigned m0 = v.x < v.y ? v.x : v.y;
      unsigned m1 = v.z < v.w ? v.z : v.w;
      if ((m0 < m1 ? m0 : m1) >= n) break;
      __builtin_amdgcn_s_sleep(1);
    }
  }
  __syncthreads();
}

// ---------- prep kernels ----------
__global__ void conv_bf16(const float* __restrict__ src, ushortT* __restrict__ dst, size_t n) {
  size_t i  = blockIdx.x * (size_t)blockDim.x + threadIdx.x;
  size_t st = (size_t)gridDim.x * blockDim.x;
  for (; i < n; i += st) dst[i] = f2bf(src[i]);
}

__global__ void prep_kv(const float* __restrict__ text, const float* __restrict__ Wk,
                        const float* __restrict__ Wv, ushortT* __restrict__ keys,
                        ushortT* __restrict__ valt) {
  __shared__ float tx[ATT];
  const int t = blockIdx.x;
  for (int i = threadIdx.x; i < ATT; i += blockDim.x) tx[i] = text[(size_t)t*ATT + i];
  __syncthreads();
  for (int a = threadIdx.x; a < 2*ATT; a += blockDim.x) {
    const int which = (a >= ATT);
    const int ar = a - which*ATT;
    const float4* w4 = (const float4*)((which ? Wv : Wk) + (size_t)ar*ATT);
    const float4* t4 = (const float4*)tx;
    float s = 0.f;
    for (int i = 0; i < ATT/4; ++i) {
      float4 w = w4[i], x = t4[i];
      s += w.x*x.x + w.y*x.y + w.z*x.z + w.w*x.w;
    }
    if (which) valt[(size_t)ar*TXT + t] = f2bf(s);       // transposed
    else       keys[(size_t)t*ATT + ar] = f2bf(s);       // row-major
  }
}

__global__ void prep_zero(float* f, unsigned* bar) {
  int i = blockIdx.x * blockDim.x + threadIdx.x;
  if (i < F_END) f[i] = 0.f;
  if (i < BAR_N) bar[i] = 0u;
}

// ---------- persistent AR kernel ----------
__global__ void __launch_bounds__(NT, 1)
ar_persist(const float* __restrict__ residual,
           const float* __restrict__ Whh_a, const float* __restrict__ Whh0g,
           const float* __restrict__ Wih1g,
           const float* __restrict__ b_a, const float* __restrict__ v_attn,
           const float* __restrict__ b0, const float* __restrict__ b1,
           const float* __restrict__ bd1, const float* __restrict__ bd2,
           const float* __restrict__ Wc, const float* __restrict__ bc,
           const float* __restrict__ Wg, const float* __restrict__ bg,
           float* __restrict__ out, void* __restrict__ wsraw)
{
  const int tid  = threadIdx.x;
  const int bid  = blockIdx.x;
  const int wid  = tid >> 6;     // 8 waves
  const int lane = tid & 63;

  const ushortT* uws = (const ushortT*)wsraw;
  float*    f   = (float*)((char*)wsraw + FBYTE);
  unsigned* bar = (unsigned*)((char*)wsraw + BBYTE);

  const ushortT* wq    = uws + O_WQ;
  const ushortT* wiha  = uws + O_WIHA;
  const ushortT* wih0s = uws + O_WIH0;
  const ushortT* whh1s = uws + O_WHH1;
  const ushortT* wd1   = uws + O_WD1;
  const ushortT* wd2   = uws + O_WD2;
  const ushortT* keys  = uws + O_KEYS;
  const ushortT* valt  = uws + O_VALT;

  // block owns units [bid*4, bid*4+4); 16 z-rows; wave wid -> rl 2w, 2w+1
  const int ub = bid*4;
  const int rlA = wid*2, rlB = wid*2 + 1;
  const int zrA = (rlA>>2)*H + ub + (rlA&3);
  const int zrB = (rlB>>2)*H + ub + (rlB&3);

  __shared__ __align__(16) ushortT lWhha[16*H];   // 32 KB
  __shared__ __align__(16) ushortT lWhh0[16*H];   // 32 KB
  __shared__ __align__(16) ushortT lWih1[16*H];   // 32 KB
  __shared__ __align__(16) ushortT lWd1[4*H];     // 8 KB
  __shared__ __align__(16) ushortT lWd2[4*H];     // 8 KB
  __shared__ __align__(16) ushortT lWq[3*H];      // 6 KB
  __shared__ __align__(16) float   lvatt[ATT];
  __shared__ __align__(16) float   lha[H], lh0[H], lh1[H];
  __shared__ __align__(16) float   shq[ATT], lctx[ATT];
  __shared__ __align__(16) float   shv[H];
  __shared__ __align__(16) float4  shx4[20];
  __shared__ float sc[TXT];
  __shared__ float zl[16], zp[16], zaH[16], z0H[16], z1H[16];
  __shared__ float cA[4], c0S[4], c1S[4], misc2[4];

  // ---- init: stage recurrent rows + decoder rows + q rows + v_attn ----
  {
    us4* dA = (us4*)lWhha; us4* dC = (us4*)lWhh0; us4* dD = (us4*)lWih1;
    #pragma unroll
    for (int j = 0; j < 2; ++j) {
      const int rl = wid*2 + j;
      const int zr = (rl>>2)*H + ub + (rl&3);
      #pragma unroll
      for (int c = 0; c < 4; ++c) {
        const int ei = c*64 + lane;
        dA[rl*256 + ei] = cvt4(*(const float4*)(Whh_a + (size_t)zr*H + ei*4));
        dC[rl*256 + ei] = cvt4(*(const float4*)(Whh0g + (size_t)zr*H + ei*4));
        dD[rl*256 + ei] = cvt4(*(const float4*)(Wih1g + (size_t)zr*H + ei*4));
      }
    }
    if (wid < 4) {
      const us4* s1 = (const us4*)(wd1 + (size_t)(bid*4 + wid)*H);
      #pragma unroll
      for (int c = 0; c < 4; ++c)
        ((us4*)lWd1)[wid*256 + c*64 + lane] = s1[c*64 + lane];
    } else {
      const int w = wid - 4;
      const us4* s2 = (const us4*)(wd2 + (size_t)(bid*4 + w)*H);
      #pragma unroll
      for (int c = 0; c < 4; ++c)
        ((us4*)lWd2)[w*256 + c*64 + lane] = s2[c*64 + lane];
    }
    for (int w = 0; w < 3; ++w) {
      const int qr = bid + w*GBK;
      if (qr < ATT) {
        const us4* sq = (const us4*)(wq + (size_t)qr*H);
        for (int i = tid; i < 256; i += NT) ((us4*)lWq)[w*256 + i] = sq[i];
      }
    }
    for (int i = tid; i < ATT; i += NT) lvatt[i] = v_attn[i];
  }
  if (tid < 16) { zaH[tid] = 0.f; z0H[tid] = 0.f; z1H[tid] = 0.f; }
  if (tid < 4)  { cA[tid] = 0.f; c0S[tid] = 0.f; c1S[tid] = 0.f; }
  __syncthreads();

  unsigned nb = 0;

  for (int s = 0; s < T_STEPS; ++s) {
    // ===== P1: z_a = Wih_a@x + zaH + b_a -> ha, ca  (zaH precomputed) =====
    if (tid < 20) shx4[tid] = cload4(f + F_X + tid*4);
    __syncthreads();
    {
      float sA = 0.f, sB = 0.f;
      if (lane < 20) {
        float4 xv = shx4[lane];
        us4 w = ((const us4*)wiha)[(size_t)zrA*20 + lane];
        sA = bf2f(w[0])*xv.x + bf2f(w[1])*xv.y + bf2f(w[2])*xv.z + bf2f(w[3])*xv.w;
        w = ((const us4*)wiha)[(size_t)zrB*20 + lane];
        sB = bf2f(w[0])*xv.x + bf2f(w[1])*xv.y + bf2f(w[2])*xv.z + bf2f(w[3])*xv.w;
      }
      sA = red64(sA) + zaH[rlA] + b_a[zrA];
      sB = red64(sB) + zaH[rlB] + b_a[zrB];
      if (lane == 0) { zl[rlA] = sA; zl[rlB] = sB; }
    }
    __syncthreads();
    if (tid < 4) {
      float iv = zl[tid], fv = zl[4+tid], gv = zl[8+tid], ov = zl[12+tid];
      float c = sigf(fv)*cA[tid] + sigf(iv)*tanhf(gv);
      float h = sigf(ov)*tanhf(c);
      cA[tid] = c;
      cstore(f + F_HA + ub + tid, h);
    }
    abar(bar, bid, ++nb);                       // A: ha ready

    // ===== P2: z0part = Wih0[:,:H]@ha + z0H + b0 ; q rows ; gate_ha =====
    cstage4(lha, f + F_HA, 256);
    __syncthreads();
    {
      float sA = dotbf(wih0s + (size_t)zrA*DIN, lha, lane);
      float sB = dotbf(wih0s + (size_t)zrB*DIN, lha, lane);
      sA = red64(sA) + z0H[rlA] + b0[zrA];
      sB = red64(sB) + z0H[rlB] + b0[zrB];
      if (lane == 0) { zp[rlA] = sA; zp[rlB] = sB; }
      if (wid < 3) {
        const int qr = bid + wid*GBK;
        if (qr < ATT) {
          float sq = red64(dotbf(lWq + wid*H, lha, lane));
          if (lane == 0) cstore(f + F_Q + qr, sq);
        }
      }
      if (bid == GATE_B && wid == 3) {
        float sg = red64(dotf(Wg, lha, lane));
        if (lane == 0) misc2[0] = sg;
      }
    }
    abar(bar, bid, ++nb);                       // B: q ready

    // ===== P3: FUSED attention (every block, fully local) ; z0fin -> h0 ; gate =====
    cstage4(shq, f + F_Q, 160);
    __syncthreads();
    for (int t = wid; t < TXT; t += 8) {        // scores, 25 positions/wave
      const us4* kp = (const us4*)(keys + (size_t)t*ATT);
      float ss = 0.f;
      for (int c = lane; c < 160; c += 64) {
        us4 k = kp[c];
        float4 q4 = ((const float4*)shq)[c];
        float4 v4 = ((const float4*)lvatt)[c];
        ss += tanhfast(bf2f(k[0]) + q4.x)*v4.x + tanhfast(bf2f(k[1]) + q4.y)*v4.y
            + tanhfast(bf2f(k[2]) + q4.z)*v4.z + tanhfast(bf2f(k[3]) + q4.w)*v4.w;
      }
      ss = red64(ss);
      if (lane == 0) sc[t] = __expf(ss);        // |ss| <= sum|v_attn| ~ 10: safe
    }
    __syncthreads();
    if (wid == 0) {                              // Z = sum(sc)
      float pz = sc[lane] + sc[64 + lane] + sc[128 + lane]
               + (lane < 8 ? sc[192 + lane] : 0.f);
      pz = red64(pz);
      if (lane == 0) misc2[1] = 1.0f / pz;
    }
    __syncthreads();
    {
      const float invZ = misc2[1];
      for (int a = tid; a < ATT; a += NT) {      // ctx from transposed vals
        const us8* vp = (const us8*)(valt + (size_t)a*TXT);
        float acc = 0.f;
        for (int j = 0; j < TXT/8; ++j) {
          us8 w = vp[j];
          #pragma unroll
          for (int e = 0; e < 8; ++e) acc += sc[j*8 + e] * bf2f(w[e]);
        }
        lctx[a] = acc * invZ;
      }
    }
    __syncthreads();
    {
      float sA = red64(dot640bf(wih0s + (size_t)zrA*DIN + H, lctx, lane)) + zp[rlA];
      float sB = red64(dot640bf(wih0s + (size_t)zrB*DIN + H, lctx, lane)) + zp[rlB];
      if (lane == 0) { zl[rlA] = sA; zl[rlB] = sB; }
    }
    __syncthreads();
    if (tid < 4) {
      float iv = zl[tid], fv = zl[4+tid], gv = zl[8+tid], ov = zl[12+tid];
      float c = sigf(fv)*c0S[tid] + sigf(iv)*tanhf(gv);
      float h = sigf(ov)*tanhf(c);
      c0S[tid] = c;
      cstore(f + F_H0 + ub + tid, h);
    }
    if (bid == GATE_B && wid == 3) {
      float sg = red64(dot640f(Wg + H, lctx, lane));
      if (lane == 0) out[T_STEPS*NMEL + s] = sigf(sg + misc2[0] + bg[0]);
    }
    abar(bar, bid, ++nb);                       // C: h0 ready

    // ===== P4: z1 = Wih1@h0 + z1H + b1 -> h1 =====
    cstage4(lh0, f + F_H0, 256);
    __syncthreads();
    {
      float sA = red64(dotbf(lWih1 + rlA*H, lh0, lane)) + z1H[rlA] + b1[zrA];
      float sB = red64(dotbf(lWih1 + rlB*H, lh0, lane)) + z1H[rlB] + b1[zrB];
      if (lane == 0) { zl[rlA] = sA; zl[rlB] = sB; }
    }
    __syncthreads();
    if (tid < 4) {
      float iv = zl[tid], fv = zl[4+tid], gv = zl[8+tid], ov = zl[12+tid];
      float c = sigf(fv)*c1S[tid] + sigf(iv)*tanhf(gv);
      float h = sigf(ov)*tanhf(c);
      c1S[tid] = c;
      cstore(f + F_H1 + ub + tid, h);
    }
    abar(bar, bid, ++nb);                       // D: h1 ready

    // ===== P5: d1 rows ; shadow: zaH(next) = Whh_a@ha =====
    cstage4(lh1, f + F_H1, 256);
    __syncthreads();
    if (wid < 4) {
      const int r = bid*4 + wid;
      float s6 = red64(dotbf(lWd1 + wid*H, lh1, lane)) + bd1[r];
      if (lane == 0) cstore(f + F_D1 + r, tanhf(s6));
    }
    {
      float pA = red64(dotbf(lWhha + rlA*H, lha, lane));
      float pB = red64(dotbf(lWhha + rlB*H, lha, lane));
      if (lane == 0) { zaH[rlA] = pA; zaH[rlB] = pB; }
    }
    abar(bar, bid, ++nb);                       // E: d1 ready

    // ===== P6: d rows ; shadow: z0H(next) = Whh0@h0 =====
    cstage4(shv, f + F_D1, 256);
    __syncthreads();
    if (wid < 4) {
      const int r = bid*4 + wid;
      float s7 = red64(dotbf(lWd2 + wid*H, shv, lane)) + bd2[r];
      if (lane == 0) cstore(f + F_D + r, tanhf(s7));
    }
    {
      float pA = red64(dotbf(lWhh0 + rlA*H, lh0, lane));
      float pB = red64(dotbf(lWhh0 + rlB*H, lh0, lane));
      if (lane == 0) { z0H[rlA] = pA; z0H[rlB] = pB; }
    }
    abar(bar, bid, ++nb);                       // F: d ready

    // ===== P7: dec_out + x (blocks 0..79) ; shadow: z1H(next) = Whh1@h1 =====
    if (bid < NMEL) cstage4(shv, f + F_D, 256);
    {
      float pA = red64(dotbf(whh1s + (size_t)zrA*H, lh1, lane));
      float pB = red64(dotbf(whh1s + (size_t)zrB*H, lh1, lane));
      if (lane == 0) { z1H[rlA] = pA; z1H[rlB] = pB; }
    }
    if (bid < NMEL) {
      __syncthreads();
      if (wid < 2) {
        const int r = wid*NMEL + bid;            // wid0: log_s, wid1: bb
        float s8 = red64(dotf(Wc + (size_t)r*H, shv, lane)) + bc[r];
        if (lane == 0) misc2[2 + wid] = s8;
      }
      __syncthreads();
      if (tid == 0) {
        const int idx = T_STEPS - 1 - s;
        const float r = residual[idx*NMEL + bid];
        const float o = (r - misc2[3]) * expf(-misc2[2]);
        out[idx*NMEL + bid] = o;
        cstore(f + F_X + bid, o);
      }
    }
    abar(bar, bid, ++nb);                       // G: x ready
  }
}

extern "C" void kernel_launch(void* const* d_in, const int* in_sizes, int n_in,
                              void* d_out, int out_size, void* d_ws, size_t ws_size,
                              hipStream_t stream) {
  const float* residual = (const float*)d_in[0];
  const float* text   = (const float*)d_in[1];
  const float* Wih_a  = (const float*)d_in[2];
  const float* Whh_a  = (const float*)d_in[3];
  const float* b_a    = (const float*)d_in[4];
  const float* Wq     = (const float*)d_in[5];
  const float* Wk     = (const float*)d_in[6];
  const float* Wv     = (const float*)d_in[7];
  const float* v_attn = (const float*)d_in[8];
  const float* Wih0   = (const float*)d_in[9];
  const float* Whh0   = (const float*)d_in[10];
  const float* b0     = (const float*)d_in[11];
  const float* Wih1   = (const float*)d_in[12];
  const float* Whh1   = (const float*)d_in[13];
  const float* b1     = (const float*)d_in[14];
  const float* Wd1    = (const float*)d_in[15];
  const float* bd1    = (const float*)d_in[16];
  const float* Wd2    = (const float*)d_in[17];
  const float* bd2    = (const float*)d_in[18];
  const float* Wc     = (const float*)d_in[19];
  const float* bc     = (const float*)d_in[20];
  const float* Wg     = (const float*)d_in[21];
  const float* bg     = (const float*)d_in[22];
  float* out = (float*)d_out;

  char* wsb = (char*)d_ws;
  ushortT*  u   = (ushortT*)wsb;
  float*    f   = (float*)(wsb + FBYTE);
  unsigned* bar = (unsigned*)(wsb + BBYTE);

  conv_bf16<<<1024, 256, 0, stream>>>(Wq,    u + O_WQ,   (size_t)ATT*H);
  conv_bf16<<<1024, 256, 0, stream>>>(Wih_a, u + O_WIHA, (size_t)4*H*NMEL);
  conv_bf16<<<1024, 256, 0, stream>>>(Wih0,  u + O_WIH0, (size_t)4*H*DIN);
  conv_bf16<<<1024, 256, 0, stream>>>(Whh1,  u + O_WHH1, (size_t)4*H*H);
  conv_bf16<<<1024, 256, 0, stream>>>(Wd1,   u + O_WD1,  (size_t)H*H);
  conv_bf16<<<1024, 256, 0, stream>>>(Wd2,   u + O_WD2,  (size_t)H*H);
  prep_kv<<<TXT, 256, 0, stream>>>(text, Wk, Wv, u + O_KEYS, u + O_VALT);
  prep_zero<<<64, 256, 0, stream>>>(f, bar);

  ar_persist<<<GBK, NT, 0, stream>>>(residual, Whh_a, Whh0, Wih1,
      b_a, v_attn, b0, b1, bd1, bd2, Wc, bc, Wg, bg, out, d_ws);
}

// Round 9
// 16827.815 us; speedup vs baseline: 2.5319x; 2.5319x over previous
//
#include <hip/hip_runtime.h>
#include <hip/hip_bf16.h>
#include <math.h>

#define GBK 256          // grid blocks (1 per CU, co-resident)
#define NT  512          // threads per block (8 waves)

constexpr int T_STEPS = 600;
constexpr int TXT     = 200;
constexpr int NMEL    = 80;
constexpr int H       = 1024;
constexpr int ATT     = 640;
constexpr int DIN     = H + ATT;   // 1664
constexpr int GATE_B  = 200;       // gate-output block (free during SC phase)

// ---- ws layout: bf16 region (ushort element offsets) ----
constexpr size_t O_WQ    = 0;                                  // 640*1024
constexpr size_t O_WIHA  = O_WQ   + (size_t)ATT*H;             // 4096*80
constexpr size_t O_WIH0  = O_WIHA + (size_t)4*H*NMEL;          // 4096*1664
constexpr size_t O_WHH1  = O_WIH0 + (size_t)4*H*DIN;           // 4096*1024
constexpr size_t O_WD1   = O_WHH1 + (size_t)4*H*H;             // 1024*1024
constexpr size_t O_WD2   = O_WD1  + (size_t)H*H;
constexpr size_t O_KEYS  = O_WD2  + (size_t)H*H;               // 200*640 row-major
constexpr size_t O_VALS  = O_KEYS + (size_t)TXT*ATT;           // 200*640 row-major
constexpr size_t O_END_U = O_VALS + (size_t)TXT*ATT;
constexpr size_t FBYTE   = ((O_END_U*2 + 255)/256)*256;
// ---- float region ----
constexpr int F_X   = 0;           // 128 (80 used)
constexpr int F_HA  = 128;         // H
constexpr int F_H0  = F_HA + H;    // H
constexpr int F_H1  = F_H0 + H;    // H
constexpr int F_Q   = F_H1 + H;    // ATT
constexpr int F_D1  = F_Q  + ATT;  // H
constexpr int F_D   = F_D1 + H;    // H
constexpr int F_SC  = F_D  + H;    // 256 (200 used: raw scores)
constexpr int F_END = F_SC + 256;
constexpr size_t BBYTE  = FBYTE + (((size_t)F_END*4 + 255)/256)*256;
// barrier flags: 64 lines x 128B; block b -> line b>>2, dword b&3
constexpr int BAR_N = 64*32;

typedef unsigned short ushortT;
typedef ushortT us4 __attribute__((ext_vector_type(4)));
typedef ushortT us8 __attribute__((ext_vector_type(8)));

__device__ __forceinline__ float bf2f(ushortT u) {
  return __uint_as_float(((unsigned)u) << 16);
}
__device__ __forceinline__ ushortT f2bf(float x) {
  __hip_bfloat16 h = __float2bfloat16(x);
  ushortT u; __builtin_memcpy(&u, &h, 2); return u;
}
__device__ __forceinline__ us4 cvt4(float4 a) {
  return us4{ f2bf(a.x), f2bf(a.y), f2bf(a.z), f2bf(a.w) };
}
__device__ __forceinline__ float sigf(float x) { return 1.0f / (1.0f + expf(-x)); }
__device__ __forceinline__ float tanhfast(float x) {
  float e = __expf(2.0f * x);
  return (e - 1.0f) / (e + 1.0f);
}

__device__ __forceinline__ float red64(float v) {
  #pragma unroll
  for (int off = 32; off > 0; off >>= 1) v += __shfl_xor(v, off, 64);
  return v;
}

// coherent accessors (LLC, cache-bypassing)
__device__ __forceinline__ float cload(const float* p) {
  return __hip_atomic_load(p, __ATOMIC_RELAXED, __HIP_MEMORY_SCOPE_AGENT);
}
__device__ __forceinline__ void cstore(float* p, float v) {
  __hip_atomic_store(p, v, __ATOMIC_RELAXED, __HIP_MEMORY_SCOPE_AGENT);
}
__device__ __forceinline__ void astore(unsigned* p, unsigned v) {
  __hip_atomic_store(p, v, __ATOMIC_RELAXED, __HIP_MEMORY_SCOPE_AGENT);
}
// 16B coherent loads (load + waitcnt fused so consumers can't be hoisted)
__device__ __forceinline__ float4 cload4(const float* p) {
  float4 v;
  asm volatile("global_load_dwordx4 %0, %1, off sc0 sc1\n\ts_waitcnt vmcnt(0)"
               : "=v"(v) : "v"(p) : "memory");
  return v;
}
__device__ __forceinline__ uint4 cloadu4(const unsigned* p) {
  uint4 v;
  asm volatile("global_load_dwordx4 %0, %1, off sc0 sc1\n\ts_waitcnt vmcnt(0)"
               : "=v"(v) : "v"(p) : "memory");
  return v;
}
__device__ __forceinline__ void cstage4(float* dst, const float* src, int nf4) {
  for (int i = threadIdx.x; i < nf4; i += NT)
    ((float4*)dst)[i] = cload4(src + i*4);
}

// ---- conflict-free dots: lane handles float4/us4 index c*64+lane ----
__device__ __forceinline__ float dotbf(const ushortT* __restrict__ Wrow,
                                       const float* __restrict__ v, int lane) {
  const us4* w4 = (const us4*)Wrow;
  const float4* v4 = (const float4*)v;
  float s = 0.f;
  #pragma unroll
  for (int c = 0; c < 4; ++c) {
    us4 w = w4[c*64 + lane];
    float4 x = v4[c*64 + lane];
    s += bf2f(w[0])*x.x + bf2f(w[1])*x.y + bf2f(w[2])*x.z + bf2f(w[3])*x.w;
  }
  return s;
}
__device__ __forceinline__ float dotf(const float* __restrict__ Wrow,
                                      const float* __restrict__ v, int lane) {
  const float4* w4 = (const float4*)Wrow;
  const float4* v4 = (const float4*)v;
  float s = 0.f;
  #pragma unroll
  for (int c = 0; c < 4; ++c) {
    float4 w = w4[c*64 + lane], x = v4[c*64 + lane];
    s += w.x*x.x + w.y*x.y + w.z*x.z + w.w*x.w;
  }
  return s;
}
// 200-length LDS dot (e-weights): lane covers t = lane, +64, +128, +192(<200)
__device__ __forceinline__ float dot200(const float* __restrict__ a,
                                        const float* __restrict__ e, int lane) {
  float s = a[lane]*e[lane] + a[64+lane]*e[64+lane] + a[128+lane]*e[128+lane];
  if (lane < 8) s += a[192+lane]*e[192+lane];
  return s;
}

// single-hop all-to-all grid barrier; packed flags -> one dwordx4 poll per lane
__device__ __forceinline__ void abar(unsigned* bar, int bid, unsigned n) {
  asm volatile("s_waitcnt vmcnt(0)" ::: "memory");
  __syncthreads();
  const int tid = threadIdx.x;
  if (tid == 0) astore(bar + (bid >> 2)*32 + (bid & 3), n);
  if (tid < 64) {
    const unsigned* p = bar + tid*32;
    while (true) {
      uint4 v = cloadu4(p);
      unsigned m0 = v.x < v.y ? v.x : v.y;
      unsigned m1 = v.z < v.w ? v.z : v.w;
      if ((m0 < m1 ? m0 : m1) >= n) break;
      __builtin_amdgcn_s_sleep(1);
    }
  }
  __syncthreads();
}

// ---------- prep kernels ----------
__global__ void conv_bf16(const float* __restrict__ src, ushortT* __restrict__ dst, size_t n) {
  size_t i  = blockIdx.x * (size_t)blockDim.x + threadIdx.x;
  size_t st = (size_t)gridDim.x * blockDim.x;
  for (; i < n; i += st) dst[i] = f2bf(src[i]);
}

__global__ void prep_kv(const float* __restrict__ text, const float* __restrict__ Wk,
                        const float* __restrict__ Wv, ushortT* __restrict__ keys,
                        ushortT* __restrict__ vals) {
  __shared__ float tx[ATT];
  const int t = blockIdx.x;
  for (int i = threadIdx.x; i < ATT; i += blockDim.x) tx[i] = text[(size_t)t*ATT + i];
  __syncthreads();
  for (int a = threadIdx.x; a < 2*ATT; a += blockDim.x) {
    const int which = (a >= ATT);
    const int ar = a - which*ATT;
    const float4* w4 = (const float4*)((which ? Wv : Wk) + (size_t)ar*ATT);
    const float4* t4 = (const float4*)tx;
    float s = 0.f;
    for (int i = 0; i < ATT/4; ++i) {
      float4 w = w4[i], x = t4[i];
      s += w.x*x.x + w.y*x.y + w.z*x.z + w.w*x.w;
    }
    (which ? vals : keys)[(size_t)t*ATT + ar] = f2bf(s);
  }
}

__global__ void prep_zero(float* f, unsigned* bar) {
  int i = blockIdx.x * blockDim.x + threadIdx.x;
  if (i < F_END) f[i] = 0.f;
  if (i < BAR_N) bar[i] = 0u;
}

// ---------- persistent AR kernel ----------
__global__ void __launch_bounds__(NT, 1)
ar_persist(const float* __restrict__ residual,
           const float* __restrict__ Whh_a, const float* __restrict__ Whh0g,
           const float* __restrict__ Wih1g,
           const float* __restrict__ b_a, const float* __restrict__ v_attn,
           const float* __restrict__ b0, const float* __restrict__ b1,
           const float* __restrict__ bd1, const float* __restrict__ bd2,
           const float* __restrict__ Wc, const float* __restrict__ bc,
           const float* __restrict__ Wg, const float* __restrict__ bg,
           float* __restrict__ out, void* __restrict__ wsraw)
{
  const int tid  = threadIdx.x;
  const int bid  = blockIdx.x;
  const int wid  = tid >> 6;     // 8 waves
  const int lane = tid & 63;

  const ushortT* uws = (const ushortT*)wsraw;
  float*    f   = (float*)((char*)wsraw + FBYTE);
  unsigned* bar = (unsigned*)((char*)wsraw + BBYTE);

  const ushortT* wq    = uws + O_WQ;
  const ushortT* wiha  = uws + O_WIHA;
  const ushortT* wih0s = uws + O_WIH0;
  const ushortT* whh1s = uws + O_WHH1;
  const ushortT* wd1   = uws + O_WD1;
  const ushortT* wd2   = uws + O_WD2;
  const ushortT* keys  = uws + O_KEYS;
  const ushortT* vals  = uws + O_VALS;

  // block owns units [bid*4, bid*4+4); 16 z-rows; wave wid -> rl 2w, 2w+1
  const int ub = bid*4;
  const int rlA = wid*2, rlB = wid*2 + 1;
  const int zrA = (rlA>>2)*H + ub + (rlA&3);
  const int zrB = (rlB>>2)*H + ub + (rlB&3);

  __shared__ __align__(16) ushortT lWhha[16*H];   // 32 KB
  __shared__ __align__(16) ushortT lWhh0[16*H];   // 32 KB
  __shared__ __align__(16) ushortT lWih1[16*H];   // 32 KB
  __shared__ __align__(16) ushortT lWd1[4*H];     // 8 KB
  __shared__ __align__(16) ushortT lWd2[4*H];     // 8 KB
  __shared__ __align__(16) ushortT lWq[3*H];      // 6 KB
  __shared__ __align__(16) float   V0[16*TXT];    // 12.8 KB: Wih0[:,H:] @ v_t
  __shared__ __align__(16) float   vg[TXT];       // Wg[H:] @ v_t (GATE_B only)
  __shared__ __align__(16) float   lvatt[ATT];
  __shared__ __align__(16) float   lha[H], lh0[H], lh1[H];
  __shared__ __align__(16) float   shv[H];
  __shared__ __align__(16) float4  shx4[20];
  __shared__ float sce[TXT];                      // raw scores -> exp'd weights
  __shared__ float wsum[8];
  __shared__ float zl[16], zp[16], zaH[16], z0H[16], z1H[16];
  __shared__ float cA[4], c0S[4], c1S[4], misc2[4];

  // ---- init: stage LDS weights ----
  {
    us4* dA = (us4*)lWhha; us4* dC = (us4*)lWhh0; us4* dD = (us4*)lWih1;
    #pragma unroll
    for (int j = 0; j < 2; ++j) {
      const int rl = wid*2 + j;
      const int zr = (rl>>2)*H + ub + (rl&3);
      #pragma unroll
      for (int c = 0; c < 4; ++c) {
        const int ei = c*64 + lane;
        dA[rl*256 + ei] = cvt4(*(const float4*)(Whh_a + (size_t)zr*H + ei*4));
        dC[rl*256 + ei] = cvt4(*(const float4*)(Whh0g + (size_t)zr*H + ei*4));
        dD[rl*256 + ei] = cvt4(*(const float4*)(Wih1g + (size_t)zr*H + ei*4));
      }
    }
    if (wid < 4) {
      const us4* s1 = (const us4*)(wd1 + (size_t)(bid*4 + wid)*H);
      #pragma unroll
      for (int c = 0; c < 4; ++c)
        ((us4*)lWd1)[wid*256 + c*64 + lane] = s1[c*64 + lane];
    } else {
      const int w = wid - 4;
      const us4* s2 = (const us4*)(wd2 + (size_t)(bid*4 + w)*H);
      #pragma unroll
      for (int c = 0; c < 4; ++c)
        ((us4*)lWd2)[w*256 + c*64 + lane] = s2[c*64 + lane];
    }
    for (int w = 0; w < 3; ++w) {
      const int qr = bid + w*GBK;
      if (qr < ATT) {
        const us4* sq = (const us4*)(wq + (size_t)qr*H);
        for (int i = tid; i < 256; i += NT) ((us4*)lWq)[w*256 + i] = sq[i];
      }
    }
    for (int i = tid; i < ATT; i += NT) lvatt[i] = v_attn[i];
  }
  // ---- init: V0[r][t] = Wih0_row[H:] . v_t  (reassociated ctx) ----
  for (int idx = tid; idx < 16*TXT; idx += NT) {
    const int r = idx / TXT, t = idx - r*TXT;
    const int zr = (r>>2)*H + ub + (r&3);
    const us8* wp = (const us8*)(wih0s + (size_t)zr*DIN + H);
    const us8* vp = (const us8*)(vals + (size_t)t*ATT);
    float acc = 0.f;
    for (int c = 0; c < ATT/8; ++c) {
      us8 w = wp[c], v = vp[c];
      #pragma unroll
      for (int e = 0; e < 8; ++e) acc += bf2f(w[e]) * bf2f(v[e]);
    }
    V0[r*TXT + t] = acc;
  }
  if (bid == GATE_B) {                      // Vg[t] = Wg[H:] . v_t
    for (int t = tid; t < TXT; t += NT) {
      const float4* wp = (const float4*)(Wg + H);
      const us4* vp = (const us4*)(vals + (size_t)t*ATT);
      float acc = 0.f;
      for (int c = 0; c < ATT/4; ++c) {
        float4 w = wp[c]; us4 v = vp[c];
        acc += w.x*bf2f(v[0]) + w.y*bf2f(v[1]) + w.z*bf2f(v[2]) + w.w*bf2f(v[3]);
      }
      vg[t] = acc;
    }
  }
  if (tid < 16) { zaH[tid] = 0.f; z0H[tid] = 0.f; z1H[tid] = 0.f; }
  if (tid < 4)  { cA[tid] = 0.f; c0S[tid] = 0.f; c1S[tid] = 0.f; }
  __syncthreads();

  unsigned nb = 0;

  for (int s = 0; s < T_STEPS; ++s) {
    // ===== P1: z_a = Wih_a@x + zaH + b_a -> ha, ca =====
    if (tid < 20) shx4[tid] = cload4(f + F_X + tid*4);
    __syncthreads();
    {
      float sA = 0.f, sB = 0.f;
      if (lane < 20) {
        float4 xv = shx4[lane];
        us4 w = ((const us4*)wiha)[(size_t)zrA*20 + lane];
        sA = bf2f(w[0])*xv.x + bf2f(w[1])*xv.y + bf2f(w[2])*xv.z + bf2f(w[3])*xv.w;
        w = ((const us4*)wiha)[(size_t)zrB*20 + lane];
        sB = bf2f(w[0])*xv.x + bf2f(w[1])*xv.y + bf2f(w[2])*xv.z + bf2f(w[3])*xv.w;
      }
      sA = red64(sA) + zaH[rlA] + b_a[zrA];
      sB = red64(sB) + zaH[rlB] + b_a[zrB];
      if (lane == 0) { zl[rlA] = sA; zl[rlB] = sB; }
    }
    __syncthreads();
    if (tid < 4) {
      float iv = zl[tid], fv = zl[4+tid], gv = zl[8+tid], ov = zl[12+tid];
      float c = sigf(fv)*cA[tid] + sigf(iv)*tanhf(gv);
      float h = sigf(ov)*tanhf(c);
      cA[tid] = c;
      cstore(f + F_HA + ub + tid, h);
    }
    abar(bar, bid, ++nb);                       // A: ha ready

    // ===== P2: zp = Wih0[:,:H]@ha + z0H + b0 ; q rows ; gate_ha =====
    cstage4(lha, f + F_HA, 256);
    __syncthreads();
    {
      float sA = dotbf(wih0s + (size_t)zrA*DIN, lha, lane);
      float sB = dotbf(wih0s + (size_t)zrB*DIN, lha, lane);
      sA = red64(sA) + z0H[rlA] + b0[zrA];
      sB = red64(sB) + z0H[rlB] + b0[zrB];
      if (lane == 0) { zp[rlA] = sA; zp[rlB] = sB; }
      if (wid < 3) {
        const int qr = bid + wid*GBK;
        if (qr < ATT) {
          float sq = red64(dotbf(lWq + wid*H, lha, lane));
          if (lane == 0) cstore(f + F_Q + qr, sq);
        }
      }
      if (bid == GATE_B && wid == 3) {
        float sg = red64(dotf(Wg, lha, lane));
        if (lane == 0) misc2[0] = sg;
      }
    }
    abar(bar, bid, ++nb);                       // B: q ready

    // ===== SC: raw scores, 1 position per block (blocks 0..199) =====
    if (bid < TXT) {
      cstage4(shv, f + F_Q, 160);
      __syncthreads();
      float p = 0.f;
      if (tid < 160) {
        const us4* kp = (const us4*)(keys + (size_t)bid*ATT);
        us4 k = kp[tid];
        float4 q4 = ((const float4*)shv)[tid];
        float4 v4 = ((const float4*)lvatt)[tid];
        p = tanhfast(bf2f(k[0]) + q4.x)*v4.x + tanhfast(bf2f(k[1]) + q4.y)*v4.y
          + tanhfast(bf2f(k[2]) + q4.z)*v4.z + tanhfast(bf2f(k[3]) + q4.w)*v4.w;
      }
      p = red64(p);
      if (lane == 0) wsum[wid] = p;
      __syncthreads();
      if (tid == 0) {
        float ss = wsum[0] + wsum[1] + wsum[2];
        cstore(f + F_SC + bid, ss);
      }
    }
    abar(bar, bid, ++nb);                       // C: scores ready

    // ===== P3: local softmax-weights ; z0 = dot200(V0,e)/Z + zp -> h0 ; gate =====
    if (tid < 50) {
      float4 v = cload4(f + F_SC + tid*4);
      ((float4*)sce)[tid] = v;
    }
    __syncthreads();
    if (tid < TXT) sce[tid] = __expf(sce[tid]);  // |score| <= sum|v_attn| ~ 10: safe
    __syncthreads();
    if (wid == 0) {
      float pz = sce[lane] + sce[64+lane] + sce[128+lane]
               + (lane < 8 ? sce[192+lane] : 0.f);
      pz = red64(pz);
      if (lane == 0) misc2[1] = 1.0f / pz;
    }
    __syncthreads();
    {
      const float invZ = misc2[1];
      float sA = red64(dot200(V0 + rlA*TXT, sce, lane)) * invZ + zp[rlA];
      float sB = red64(dot200(V0 + rlB*TXT, sce, lane)) * invZ + zp[rlB];
      if (lane == 0) { zl[rlA] = sA; zl[rlB] = sB; }
    }
    __syncthreads();
    if (tid < 4) {
      float iv = zl[tid], fv = zl[4+tid], gv = zl[8+tid], ov = zl[12+tid];
      float c = sigf(fv)*c0S[tid] + sigf(iv)*tanhf(gv);
      float h = sigf(ov)*tanhf(c);
      c0S[tid] = c;
      cstore(f + F_H0 + ub + tid, h);
    }
    if (bid == GATE_B && wid == 3) {
      float sg = red64(dot200(vg, sce, lane)) * misc2[1];
      if (lane == 0) out[T_STEPS*NMEL + s] = sigf(sg + misc2[0] + bg[0]);
    }
    abar(bar, bid, ++nb);                       // D: h0 ready

    // ===== P4: z1 = Wih1@h0 + z1H + b1 -> h1 =====
    cstage4(lh0, f + F_H0, 256);
    __syncthreads();
    {
      float sA = red64(dotbf(lWih1 + rlA*H, lh0, lane)) + z1H[rlA] + b1[zrA];
      float sB = red64(dotbf(lWih1 + rlB*H, lh0, lane)) + z1H[rlB] + b1[zrB];
      if (lane == 0) { zl[rlA] = sA; zl[rlB] = sB; }
    }
    __syncthreads();
    if (tid < 4) {
      float iv = zl[tid], fv = zl[4+tid], gv = zl[8+tid], ov = zl[12+tid];
      float c = sigf(fv)*c1S[tid] + sigf(iv)*tanhf(gv);
      float h = sigf(ov)*tanhf(c);
      c1S[tid] = c;
      cstore(f + F_H1 + ub + tid, h);
    }
    abar(bar, bid, ++nb);                       // E: h1 ready

    // ===== P5: d1 rows ; shadow zaH(next) = Whh_a@ha =====
    cstage4(lh1, f + F_H1, 256);
    __syncthreads();
    if (wid < 4) {
      const int r = bid*4 + wid;
      float s6 = red64(dotbf(lWd1 + wid*H, lh1, lane)) + bd1[r];
      if (lane == 0) cstore(f + F_D1 + r, tanhf(s6));
    }
    {
      float pA = red64(dotbf(lWhha + rlA*H, lha, lane));
      float pB = red64(dotbf(lWhha + rlB*H, lha, lane));
      if (lane == 0) { zaH[rlA] = pA; zaH[rlB] = pB; }
    }
    abar(bar, bid, ++nb);                       // F: d1 ready

    // ===== P6: d rows ; shadow z0H(next) = Whh0@h0 =====
    cstage4(shv, f + F_D1, 256);
    __syncthreads();
    if (wid < 4) {
      const int r = bid*4 + wid;
      float s7 = red64(dotbf(lWd2 + wid*H, shv, lane)) + bd2[r];
      if (lane == 0) cstore(f + F_D + r, tanhf(s7));
    }
    {
      float pA = red64(dotbf(lWhh0 + rlA*H, lh0, lane));
      float pB = red64(dotbf(lWhh0 + rlB*H, lh0, lane));
      if (lane == 0) { z0H[rlA] = pA; z0H[rlB] = pB; }
    }
    abar(bar, bid, ++nb);                       // G: d ready

    // ===== P7: dec_out + x (blocks 0..79) ; shadow z1H(next) = Whh1@h1 =====
    if (bid < NMEL) cstage4(shv, f + F_D, 256);
    {
      float pA = red64(dotbf(whh1s + (size_t)zrA*H, lh1, lane));
      float pB = red64(dotbf(whh1s + (size_t)zrB*H, lh1, lane));
      if (lane == 0) { z1H[rlA] = pA; z1H[rlB] = pB; }
    }
    if (bid < NMEL) {
      __syncthreads();
      if (wid < 2) {
        const int r = wid*NMEL + bid;            // wid0: log_s, wid1: bb
        float s8 = red64(dotf(Wc + (size_t)r*H, shv, lane)) + bc[r];
        if (lane == 0) misc2[2 + wid] = s8;
      }
      __syncthreads();
      if (tid == 0) {
        const int idx = T_STEPS - 1 - s;
        const float r = residual[idx*NMEL + bid];
        const float o = (r - misc2[3]) * expf(-misc2[2]);
        out[idx*NMEL + bid] = o;
        cstore(f + F_X + bid, o);
      }
    }
    abar(bar, bid, ++nb);                       // H: x ready
  }
}

extern "C" void kernel_launch(void* const* d_in, const int* in_sizes, int n_in,
                              void* d_out, int out_size, void* d_ws, size_t ws_size,
                              hipStream_t stream) {
  const float* residual = (const float*)d_in[0];
  const float* text   = (const float*)d_in[1];
  const float* Wih_a  = (const float*)d_in[2];
  const float* Whh_a  = (const float*)d_in[3];
  const float* b_a    = (const float*)d_in[4];
  const float* Wq     = (const float*)d_in[5];
  const float* Wk     = (const float*)d_in[6];
  const float* Wv     = (const float*)d_in[7];
  const float* v_attn = (const float*)d_in[8];
  const float* Wih0   = (const float*)d_in[9];
  const float* Whh0   = (const float*)d_in[10];
  const float* b0     = (const float*)d_in[11];
  const float* Wih1   = (const float*)d_in[12];
  const float* Whh1   = (const float*)d_in[13];
  const float* b1     = (const float*)d_in[14];
  const float* Wd1    = (const float*)d_in[15];
  const float* bd1    = (const float*)d_in[16];
  const float* Wd2    = (const float*)d_in[17];
  const float* bd2    = (const float*)d_in[18];
  const float* Wc     = (const float*)d_in[19];
  const float* bc     = (const float*)d_in[20];
  const float* Wg     = (const float*)d_in[21];
  const float* bg     = (const float*)d_in[22];
  float* out = (float*)d_out;

  char* wsb = (char*)d_ws;
  ushortT*  u   = (ushortT*)wsb;
  float*    f   = (float*)(wsb + FBYTE);
  unsigned* bar = (unsigned*)(wsb + BBYTE);

  conv_bf16<<<1024, 256, 0, stream>>>(Wq,    u + O_WQ,   (size_t)ATT*H);
  conv_bf16<<<1024, 256, 0, stream>>>(Wih_a, u + O_WIHA, (size_t)4*H*NMEL);
  conv_bf16<<<1024, 256, 0, stream>>>(Wih0,  u + O_WIH0, (size_t)4*H*DIN);
  conv_bf16<<<1024, 256, 0, stream>>>(Whh1,  u + O_WHH1, (size_t)4*H*H);
  conv_bf16<<<1024, 256, 0, stream>>>(Wd1,   u + O_WD1,  (size_t)H*H);
  conv_bf16<<<1024, 256, 0, stream>>>(Wd2,   u + O_WD2,  (size_t)H*H);
  prep_kv<<<TXT, 256, 0, stream>>>(text, Wk, Wv, u + O_KEYS, u + O_VALS);
  prep_zero<<<64, 256, 0, stream>>>(f, bar);

  ar_persist<<<GBK, NT, 0, stream>>>(residual, Whh_a, Whh0, Wih1,
      b_a, v_attn, b0, b1, bd1, bd2, Wc, bc, Wg, bg, out, d_ws);
}